// Round 1
// baseline (534.787 us; speedup 1.0000x reference)
//
#include <hip/hip_runtime.h>

// TxModel: B=16384, K=64, DIN=49, D=16, NH=2, HD=8, FF=32
#define NB    16384
#define SEQ   64
#define DINV  49
#define DM    16
#define HDIM  8
#define FFD   32
#define EPSV  1e-5f

#define XTILE (SEQ * DINV)   // 3136 floats per batch element
#define KV_STRIDE 40         // 16 k + 4 pad + 16 v + 4 pad -> 160B rows, 16B aligned

__global__ __launch_bounds__(128)
void tx_fused(const float* __restrict__ x,
              const float* __restrict__ proj_w, const float* __restrict__ proj_b,
              const float* __restrict__ pos,
              const float* __restrict__ in_proj_w, const float* __restrict__ in_proj_b,
              const float* __restrict__ out_w, const float* __restrict__ out_b,
              const float* __restrict__ ln1_g, const float* __restrict__ ln1_b,
              const float* __restrict__ lin1_w, const float* __restrict__ lin1_b,
              const float* __restrict__ lin2_w, const float* __restrict__ lin2_b,
              const float* __restrict__ ln2_g, const float* __restrict__ ln2_b,
              const float* __restrict__ head_w, const float* __restrict__ head_b,
              float* __restrict__ out)
{
    // Per-wave region: x tile (3136 floats) later overlaid by kv rows (64*40=2560)
    __shared__ __align__(16) float lds[2][XTILE];

    const int tid  = threadIdx.x;
    const int w    = tid >> 6;      // wave id within block (0/1) -> batch element
    const int lane = tid & 63;      // sequence position k
    const int b    = blockIdx.x * 2 + w;

    // ---- stage x for both batch elems: 6272 contiguous floats, coalesced float4 ----
    {
        const float4* src = (const float4*)(x + (size_t)blockIdx.x * (2 * XTILE));
        float4* dst = (float4*)(&lds[0][0]);
        #pragma unroll
        for (int it = 0; it < 13; ++it) {
            int idx = tid + it * 128;
            if (idx < (2 * XTILE) / 4) dst[idx] = src[idx];
        }
    }
    __syncthreads();

    // ---- pull my row of x into registers (stride 49: odd -> only free 2-way bank alias) ----
    float xr[DINV];
    {
        const float* xrow = &lds[w][lane * DINV];
        #pragma unroll
        for (int i = 0; i < DINV; ++i) xr[i] = xrow[i];
    }

    // ---- h = x @ proj_w^T + proj_b + pos   (weights: uniform -> scalar loads) ----
    float h[DM];
    #pragma unroll
    for (int d = 0; d < DM; ++d) {
        float a = 0.f;
        #pragma unroll
        for (int i = 0; i < DINV; ++i) a = fmaf(xr[i], proj_w[d * DINV + i], a);
        h[d] = a + proj_b[d] + pos[lane * DM + d];
    }

    // ---- qkv = h @ in_proj_w^T + in_proj_b ----
    float q[DM], kk[DM], vv[DM];
    #pragma unroll
    for (int e = 0; e < DM; ++e) {
        float a = in_proj_b[e];
        #pragma unroll
        for (int d = 0; d < DM; ++d) a = fmaf(h[d], in_proj_w[e * DM + d], a);
        q[e] = a;
    }
    #pragma unroll
    for (int e = 0; e < DM; ++e) {
        float a = in_proj_b[DM + e];
        #pragma unroll
        for (int d = 0; d < DM; ++d) a = fmaf(h[d], in_proj_w[(DM + e) * DM + d], a);
        kk[e] = a;
    }
    #pragma unroll
    for (int e = 0; e < DM; ++e) {
        float a = in_proj_b[2 * DM + e];
        #pragma unroll
        for (int d = 0; d < DM; ++d) a = fmaf(h[d], in_proj_w[(2 * DM + e) * DM + d], a);
        vv[e] = a;
    }

    __syncthreads();   // all x reads done before kv overlays the x tile

    // ---- write my k/v row into LDS (row stride 40 floats keeps 16B alignment) ----
    {
        float4* kvrow = (float4*)(&lds[w][0] + lane * KV_STRIDE);
        kvrow[0] = make_float4(kk[0],  kk[1],  kk[2],  kk[3]);
        kvrow[1] = make_float4(kk[4],  kk[5],  kk[6],  kk[7]);
        kvrow[2] = make_float4(kk[8],  kk[9],  kk[10], kk[11]);
        kvrow[3] = make_float4(kk[12], kk[13], kk[14], kk[15]);
        kvrow[5] = make_float4(vv[0],  vv[1],  vv[2],  vv[3]);
        kvrow[6] = make_float4(vv[4],  vv[5],  vv[6],  vv[7]);
        kvrow[7] = make_float4(vv[8],  vv[9],  vv[10], vv[11]);
        kvrow[8] = make_float4(vv[12], vv[13], vv[14], vv[15]);
    }
    __syncthreads();

    // ---- attention: fused scores/softmax/ctx, no max-subtraction (scores << 1) ----
    float l0 = 0.f, l1 = 0.f;
    float ctx[DM];
    #pragma unroll
    for (int d = 0; d < DM; ++d) ctx[d] = 0.f;
    const float* kv = &lds[w][0];
    const float scale = 0.3535533905932738f;  // 1/sqrt(8)

    #pragma unroll 4
    for (int j = 0; j < SEQ; ++j) {
        const float4* kr = (const float4*)(kv + j * KV_STRIDE);  // uniform -> broadcast b128
        float4 k0 = kr[0], k1 = kr[1], k2 = kr[2], k3 = kr[3];
        float4 v0 = kr[5], v1 = kr[6], v2 = kr[7], v3 = kr[8];
        float s0 = fmaf(q[0], k0.x, fmaf(q[1], k0.y, fmaf(q[2], k0.z, fmaf(q[3], k0.w,
                   fmaf(q[4], k1.x, fmaf(q[5], k1.y, fmaf(q[6], k1.z, q[7] * k1.w)))))));
        float s1 = fmaf(q[8], k2.x, fmaf(q[9], k2.y, fmaf(q[10], k2.z, fmaf(q[11], k2.w,
                   fmaf(q[12], k3.x, fmaf(q[13], k3.y, fmaf(q[14], k3.z, q[15] * k3.w)))))));
        float p0 = __expf(s0 * scale);
        float p1 = __expf(s1 * scale);
        l0 += p0; l1 += p1;
        ctx[0]  = fmaf(p0, v0.x, ctx[0]);  ctx[1]  = fmaf(p0, v0.y, ctx[1]);
        ctx[2]  = fmaf(p0, v0.z, ctx[2]);  ctx[3]  = fmaf(p0, v0.w, ctx[3]);
        ctx[4]  = fmaf(p0, v1.x, ctx[4]);  ctx[5]  = fmaf(p0, v1.y, ctx[5]);
        ctx[6]  = fmaf(p0, v1.z, ctx[6]);  ctx[7]  = fmaf(p0, v1.w, ctx[7]);
        ctx[8]  = fmaf(p1, v2.x, ctx[8]);  ctx[9]  = fmaf(p1, v2.y, ctx[9]);
        ctx[10] = fmaf(p1, v2.z, ctx[10]); ctx[11] = fmaf(p1, v2.w, ctx[11]);
        ctx[12] = fmaf(p1, v3.x, ctx[12]); ctx[13] = fmaf(p1, v3.y, ctx[13]);
        ctx[14] = fmaf(p1, v3.z, ctx[14]); ctx[15] = fmaf(p1, v3.w, ctx[15]);
    }
    {
        float inv0 = 1.f / l0, inv1 = 1.f / l1;
        #pragma unroll
        for (int e = 0; e < HDIM; ++e) { ctx[e] *= inv0; ctx[HDIM + e] *= inv1; }
    }

    // ---- attn_out = ctx @ out_w^T + out_b; residual; LN1 ----
    float hn[DM];
    #pragma unroll
    for (int o = 0; o < DM; ++o) {
        float a = out_b[o];
        #pragma unroll
        for (int d = 0; d < DM; ++d) a = fmaf(ctx[d], out_w[o * DM + d], a);
        hn[o] = h[o] + a;
    }
    {
        float m = 0.f;
        #pragma unroll
        for (int d = 0; d < DM; ++d) m += hn[d];
        m *= (1.f / DM);
        float v = 0.f;
        #pragma unroll
        for (int d = 0; d < DM; ++d) { float t = hn[d] - m; v = fmaf(t, t, v); }
        v *= (1.f / DM);
        float inv = rsqrtf(v + EPSV);
        #pragma unroll
        for (int d = 0; d < DM; ++d) h[d] = (hn[d] - m) * inv * ln1_g[d] + ln1_b[d];
    }

    // ---- FFN: relu(h @ lin1_w^T + b1) @ lin2_w^T + b2; residual; LN2 ----
    float ffv[FFD];
    #pragma unroll
    for (int f = 0; f < FFD; ++f) {
        float a = lin1_b[f];
        #pragma unroll
        for (int d = 0; d < DM; ++d) a = fmaf(h[d], lin1_w[f * DM + d], a);
        ffv[f] = fmaxf(a, 0.f);
    }
    #pragma unroll
    for (int d = 0; d < DM; ++d) {
        float a = lin2_b[d];
        #pragma unroll
        for (int f = 0; f < FFD; ++f) a = fmaf(ffv[f], lin2_w[d * FFD + f], a);
        hn[d] = h[d] + a;
    }
    {
        float m = 0.f;
        #pragma unroll
        for (int d = 0; d < DM; ++d) m += hn[d];
        m *= (1.f / DM);
        float v = 0.f;
        #pragma unroll
        for (int d = 0; d < DM; ++d) { float t = hn[d] - m; v = fmaf(t, t, v); }
        v *= (1.f / DM);
        float inv = rsqrtf(v + EPSV);
        #pragma unroll
        for (int d = 0; d < DM; ++d) h[d] = (hn[d] - m) * inv * ln2_g[d] + ln2_b[d];
    }

    // ---- mean pool over K + scalar head: wave-level reduce ----
    float part = 0.f;
    #pragma unroll
    for (int d = 0; d < DM; ++d) part = fmaf(h[d], head_w[d], part);
    part *= (1.f / SEQ);
    #pragma unroll
    for (int off = 32; off > 0; off >>= 1) part += __shfl_down(part, off, 64);
    if (lane == 0) out[b] = part + head_b[0];
}

extern "C" void kernel_launch(void* const* d_in, const int* in_sizes, int n_in,
                              void* d_out, int out_size, void* d_ws, size_t ws_size,
                              hipStream_t stream) {
    const float* x         = (const float*)d_in[0];
    const float* proj_w    = (const float*)d_in[1];
    const float* proj_b    = (const float*)d_in[2];
    const float* pos       = (const float*)d_in[3];
    const float* in_proj_w = (const float*)d_in[4];
    const float* in_proj_b = (const float*)d_in[5];
    const float* out_w     = (const float*)d_in[6];
    const float* out_b     = (const float*)d_in[7];
    const float* ln1_g     = (const float*)d_in[8];
    const float* ln1_b     = (const float*)d_in[9];
    const float* lin1_w    = (const float*)d_in[10];
    const float* lin1_b    = (const float*)d_in[11];
    const float* lin2_w    = (const float*)d_in[12];
    const float* lin2_b    = (const float*)d_in[13];
    const float* ln2_g     = (const float*)d_in[14];
    const float* ln2_b     = (const float*)d_in[15];
    const float* head_w    = (const float*)d_in[16];
    const float* head_b    = (const float*)d_in[17];

    tx_fused<<<NB / 2, 128, 0, stream>>>(
        x, proj_w, proj_b, pos, in_proj_w, in_proj_b, out_w, out_b,
        ln1_g, ln1_b, lin1_w, lin1_b, lin2_w, lin2_b, ln2_g, ln2_b,
        head_w, head_b, (float*)d_out);
}

// Round 2
// 457.489 us; speedup vs baseline: 1.1690x; 1.1690x over previous
//
#include <hip/hip_runtime.h>

// TxModel: B=16384, K=64 tokens, DIN=49, D=16, NH=2, HD=8, FF=32
// One wave (64 threads) per batch element. All GEMMs via mfma_f32_16x16x32_bf16.
// M=64 tokens = 4 M-tiles; C-layout: row=(lane>>4)*4+reg, col=lane&15;
// A-layout: m=lane&15, k=(lane>>4)*8+j; B-layout: n=lane&15, k=(lane>>4)*8+j.

#define R1   0      // [64][72] bf16: x rows -> P rows; aliased as F1 fp32 rows stride 36
#define R1S  72
#define R2   4608   // [64][40] bf16: h / q / ctx / hln / ff rows (cols 16..31 zeroed)
#define R2S  40
#define R3   7168   // [64][40] bf16: k rows (cols 0..15)
#define R3S  40
#define VT   9728   // [16][72] bf16: v transposed [dim][token]
#define VTS  72
#define SMTOT 10880 // shorts = 21760 B -> 7 blocks/CU

typedef __bf16 v8bf __attribute__((ext_vector_type(8)));
typedef float  v4f  __attribute__((ext_vector_type(4)));

static __device__ __forceinline__ short f2bs(float f) {
    __bf16 h = (__bf16)f;
    return __builtin_bit_cast(short, h);
}
static __device__ __forceinline__ int pk2(float a, float b) {
    unsigned lo = (unsigned short)f2bs(a);
    unsigned hi = (unsigned short)f2bs(b);
    return (int)(lo | (hi << 16));
}
#define MFMA(a, b, c) __builtin_amdgcn_mfma_f32_16x16x32_bf16((a), (b), (c), 0, 0, 0)

__global__ __launch_bounds__(64)
void tx_mfma(const float* __restrict__ x,
             const float* __restrict__ proj_w, const float* __restrict__ proj_b,
             const float* __restrict__ pos,
             const float* __restrict__ in_proj_w, const float* __restrict__ in_proj_b,
             const float* __restrict__ out_w, const float* __restrict__ out_b,
             const float* __restrict__ ln1_g, const float* __restrict__ ln1_b,
             const float* __restrict__ lin1_w, const float* __restrict__ lin1_b,
             const float* __restrict__ lin2_w, const float* __restrict__ lin2_b,
             const float* __restrict__ ln2_g, const float* __restrict__ ln2_b,
             const float* __restrict__ head_w, const float* __restrict__ head_b,
             float* __restrict__ out)
{
    __shared__ __align__(16) short sm[SMTOT];
    float* F1 = (float*)sm;   // fp32 row view of R1, row stride 36 floats (144 B)

    const int lane = threadIdx.x;
    const int g = lane >> 4;     // lane group (quad of 16)
    const int c = lane & 15;     // col within tile
    const int b = blockIdx.x;

    v8bf zfrag;
    #pragma unroll
    for (int j = 0; j < 8; ++j) zfrag[j] = (__bf16)0.f;

    // ---- weight B-frags (global, L2-cached; per-lane row = c) ----
    v8bf Bp[2], Bq[3], Bo, Bl1[2], Bl2;
    #pragma unroll
    for (int s = 0; s < 2; ++s)
        #pragma unroll
        for (int j = 0; j < 8; ++j) {
            int k = 32*s + g*8 + j;
            Bp[s][j] = (k < 49) ? (__bf16)proj_w[c*49 + k] : (__bf16)0.f;
        }
    #pragma unroll
    for (int nt = 0; nt < 3; ++nt)
        #pragma unroll
        for (int j = 0; j < 8; ++j) {
            int k = g*8 + j;
            Bq[nt][j] = (k < 16) ? (__bf16)in_proj_w[(nt*16 + c)*16 + k] : (__bf16)0.f;
        }
    #pragma unroll
    for (int j = 0; j < 8; ++j) {
        int k = g*8 + j;
        Bo[j] = (k < 16) ? (__bf16)out_w[c*16 + k] : (__bf16)0.f;
    }
    #pragma unroll
    for (int nt = 0; nt < 2; ++nt)
        #pragma unroll
        for (int j = 0; j < 8; ++j) {
            int k = g*8 + j;
            Bl1[nt][j] = (k < 16) ? (__bf16)lin1_w[(nt*16 + c)*16 + k] : (__bf16)0.f;
        }
    #pragma unroll
    for (int j = 0; j < 8; ++j) {
        int k = g*8 + j;
        Bl2[j] = (__bf16)lin2_w[c*32 + k];   // K=32 all real
    }

    // ---- stage x -> R1 bf16 rows [64][72], coalesced float4 loads ----
    const float4* xb4 = (const float4*)(x + (size_t)b * 3136);
    #pragma unroll 4
    for (int i = 0; i < 12; ++i) {
        int idx = i*64 + lane;
        float4 v = xb4[idx];
        float vv[4] = {v.x, v.y, v.z, v.w};
        int flat = idx*4;
        #pragma unroll
        for (int e = 0; e < 4; ++e) {
            int f = flat + e, row = f / 49, col = f - row*49;
            sm[R1 + row*R1S + col] = f2bs(vv[e]);
        }
    }
    if (lane < 16) {
        int idx = 768 + lane;
        float4 v = xb4[idx];
        float vv[4] = {v.x, v.y, v.z, v.w};
        int flat = idx*4;
        #pragma unroll
        for (int e = 0; e < 4; ++e) {
            int f = flat + e, row = f / 49, col = f - row*49;
            sm[R1 + row*R1S + col] = f2bs(vv[e]);
        }
    }
    // zero pads: x cols 49..63 (NaN-guard for A-frags), R2 cols 16..31
    #pragma unroll
    for (int j = 49; j < 64; ++j) sm[R1 + lane*R1S + j] = 0;
    {
        int4 z = {0, 0, 0, 0};
        *(int4*)&sm[R2 + lane*R2S + 16] = z;
        *(int4*)&sm[R2 + lane*R2S + 24] = z;
    }
    __syncthreads();

    // ---- proj: h = x @ proj_w^T  (C-layout) ----
    v4f hC[4];
    #pragma unroll
    for (int t = 0; t < 4; ++t) {
        v4f acc = {0.f, 0.f, 0.f, 0.f};
        #pragma unroll
        for (int s = 0; s < 2; ++s) {
            v8bf a = *(const v8bf*)&sm[R1 + (t*16 + c)*R1S + 32*s + g*8];
            acc = MFMA(a, Bp[s], acc);
        }
        hC[t] = acc;
    }
    __syncthreads();
    // scatter h fp32 -> F1 rows
    #pragma unroll
    for (int t = 0; t < 4; ++t)
        #pragma unroll
        for (int r = 0; r < 4; ++r)
            F1[(t*16 + g*4 + r)*36 + c] = hC[t][r];
    __syncthreads();

    // ---- per-lane (lane=token): h += proj_b + pos; keep fp32; write bf16 row ----
    float hrow[16];
    {
        const float4* fr = (const float4*)&F1[lane*36];
        const float4* pr = (const float4*)&pos[lane*16];
        #pragma unroll
        for (int i = 0; i < 4; ++i) {
            float4 a = fr[i], p = pr[i];
            hrow[i*4+0] = a.x + proj_b[i*4+0] + p.x;
            hrow[i*4+1] = a.y + proj_b[i*4+1] + p.y;
            hrow[i*4+2] = a.z + proj_b[i*4+2] + p.z;
            hrow[i*4+3] = a.w + proj_b[i*4+3] + p.w;
        }
        int4 w0, w1;
        w0.x = pk2(hrow[0], hrow[1]);  w0.y = pk2(hrow[2], hrow[3]);
        w0.z = pk2(hrow[4], hrow[5]);  w0.w = pk2(hrow[6], hrow[7]);
        w1.x = pk2(hrow[8], hrow[9]);  w1.y = pk2(hrow[10], hrow[11]);
        w1.z = pk2(hrow[12], hrow[13]); w1.w = pk2(hrow[14], hrow[15]);
        *(int4*)&sm[R2 + lane*R2S + 0] = w0;
        *(int4*)&sm[R2 + lane*R2S + 8] = w1;
    }
    __syncthreads();

    // ---- qkv = h @ in_proj_w^T ----
    v4f qC[4], kC[4], vC[4];
    #pragma unroll
    for (int t = 0; t < 4; ++t) {
        v8bf a = *(const v8bf*)&sm[R2 + (t*16 + c)*R2S + g*8];
        v4f z = {0.f, 0.f, 0.f, 0.f};
        qC[t] = MFMA(a, Bq[0], z);
        kC[t] = MFMA(a, Bq[1], z);
        vC[t] = MFMA(a, Bq[2], z);
    }
    __syncthreads();
    {
        float bq = in_proj_b[c], bk = in_proj_b[16 + c], bv = in_proj_b[32 + c];
        #pragma unroll
        for (int t = 0; t < 4; ++t)
            #pragma unroll
            for (int r = 0; r < 4; ++r) {
                int tok = t*16 + g*4 + r;
                sm[R2 + tok*R2S + c] = f2bs(qC[t][r] + bq);   // q rows (overwrite h rows)
                sm[R3 + tok*R3S + c] = f2bs(kC[t][r] + bk);   // k rows
                sm[VT + c*VTS + tok] = f2bs(vC[t][r] + bv);   // v transposed
            }
    }
    __syncthreads();

    // ---- attention ----
    v8bf aq[4];
    #pragma unroll
    for (int tq = 0; tq < 4; ++tq) {
        v8bf a = zfrag;
        if (g < 2) a = *(const v8bf*)&sm[R2 + (tq*16 + c)*R2S + g*8];
        aq[tq] = a;
    }
    const float SC = 0.510069729f;   // log2(e)/sqrt(8)
    v4f ctxC[2][4];
    #pragma unroll
    for (int h = 0; h < 2; ++h) {
        // B-frags for scores: head-masked k rows (head dims at k = h*8..h*8+7)
        v8bf bk4[4];
        #pragma unroll
        for (int tj = 0; tj < 4; ++tj) {
            v8bf bb = zfrag;
            if (g == h) bb = *(const v8bf*)&sm[R3 + (tj*16 + c)*R3S + g*8];
            bk4[tj] = bb;
        }
        // scores -> exp -> scatter P rows (R1; x dead)
        #pragma unroll
        for (int tq = 0; tq < 4; ++tq)
            #pragma unroll
            for (int tj = 0; tj < 4; ++tj) {
                v4f z = {0.f, 0.f, 0.f, 0.f};
                v4f s = MFMA(aq[tq], bk4[tj], z);
                #pragma unroll
                for (int r = 0; r < 4; ++r) {
                    float p = exp2f(s[r] * SC);
                    sm[R1 + (tq*16 + g*4 + r)*R1S + tj*16 + c] = f2bs(p);
                }
            }
        __syncthreads();
        // ctx_u = P @ v  (+ ones column -> row sum l in col 8 (h0) / col 7 (h1))
        v8bf bv0, bv1;
        #pragma unroll
        for (int s2 = 0; s2 < 2; ++s2) {
            v8bf bb = zfrag;
            bool act = (h == 0) ? (c < 8) : (c >= 8);
            int onecol = (h == 0) ? 8 : 7;
            if (act) bb = *(const v8bf*)&sm[VT + c*VTS + 32*s2 + g*8];
            else if (c == onecol) {
                #pragma unroll
                for (int j = 0; j < 8; ++j) bb[j] = (__bf16)1.f;
            }
            if (s2) bv1 = bb; else bv0 = bb;
        }
        #pragma unroll
        for (int tq = 0; tq < 4; ++tq) {
            v4f acc = {0.f, 0.f, 0.f, 0.f};
            acc = MFMA(*(const v8bf*)&sm[R1 + (tq*16 + c)*R1S + 0  + g*8], bv0, acc);
            acc = MFMA(*(const v8bf*)&sm[R1 + (tq*16 + c)*R1S + 32 + g*8], bv1, acc);
            ctxC[h][tq] = acc;
        }
        __syncthreads();
    }

    // ---- ctx scatter (bf16 rows, R2) + l scatter (fp32, F1 cols 16/17) ----
    #pragma unroll
    for (int t = 0; t < 4; ++t)
        #pragma unroll
        for (int r = 0; r < 4; ++r) {
            int tok = t*16 + g*4 + r;
            float cv = (c < 8) ? ctxC[0][t][r] : ctxC[1][t][r];
            sm[R2 + tok*R2S + c] = f2bs(cv);
            if (c == 8) F1[tok*36 + 16] = ctxC[0][t][r];   // l0
            if (c == 7) F1[tok*36 + 17] = ctxC[1][t][r];   // l1
        }
    __syncthreads();

    // ---- out-proj ----
    v4f oC[4];
    #pragma unroll
    for (int t = 0; t < 4; ++t) {
        v8bf a = *(const v8bf*)&sm[R2 + (t*16 + c)*R2S + g*8];
        v4f z = {0.f, 0.f, 0.f, 0.f};
        oC[t] = MFMA(a, Bo, z);
    }
    __syncthreads();
    #pragma unroll
    for (int t = 0; t < 4; ++t)
        #pragma unroll
        for (int r = 0; r < 4; ++r)
            F1[(t*16 + g*4 + r)*36 + c] = oC[t][r];
    __syncthreads();

    // ---- per-lane: attn_out/l + out_b, residual, LN1; write hln bf16 row ----
    float hln[16];
    {
        const float4* fr = (const float4*)&F1[lane*36];
        float l0 = F1[lane*36 + 16], l1 = F1[lane*36 + 17];
        float inv0 = 1.f / l0, inv1 = 1.f / l1;
        float hn[16];
        float mean = 0.f;
        #pragma unroll
        for (int i = 0; i < 4; ++i) {
            float4 a = fr[i];
            float av[4] = {a.x, a.y, a.z, a.w};
            #pragma unroll
            for (int e = 0; e < 4; ++e) {
                int d = i*4 + e;
                float ao = av[e] * (d < 8 ? inv0 : inv1) + out_b[d];
                hn[d] = hrow[d] + ao;
                mean += hn[d];
            }
        }
        mean *= (1.f/16.f);
        float var = 0.f;
        #pragma unroll
        for (int d = 0; d < 16; ++d) { float t = hn[d] - mean; var = fmaf(t, t, var); }
        var *= (1.f/16.f);
        float is = rsqrtf(var + 1e-5f);
        #pragma unroll
        for (int d = 0; d < 16; ++d) hln[d] = (hn[d] - mean) * is * ln1_g[d] + ln1_b[d];

        int4 w0, w1;
        w0.x = pk2(hln[0], hln[1]);   w0.y = pk2(hln[2], hln[3]);
        w0.z = pk2(hln[4], hln[5]);   w0.w = pk2(hln[6], hln[7]);
        w1.x = pk2(hln[8], hln[9]);   w1.y = pk2(hln[10], hln[11]);
        w1.z = pk2(hln[12], hln[13]); w1.w = pk2(hln[14], hln[15]);
        *(int4*)&sm[R2 + lane*R2S + 0] = w0;
        *(int4*)&sm[R2 + lane*R2S + 8] = w1;
    }
    __syncthreads();

    // ---- FFN lin1 (+bias, relu) -> ff rows (32 cols) ----
    v4f f1C[2][4];
    #pragma unroll
    for (int t = 0; t < 4; ++t) {
        v8bf a = *(const v8bf*)&sm[R2 + (t*16 + c)*R2S + g*8];
        v4f z = {0.f, 0.f, 0.f, 0.f};
        f1C[0][t] = MFMA(a, Bl1[0], z);
        f1C[1][t] = MFMA(a, Bl1[1], z);
    }
    __syncthreads();
    {
        float b0 = lin1_b[c], b1 = lin1_b[16 + c];
        #pragma unroll
        for (int nt = 0; nt < 2; ++nt)
            #pragma unroll
            for (int t = 0; t < 4; ++t)
                #pragma unroll
                for (int r = 0; r < 4; ++r) {
                    int tok = t*16 + g*4 + r;
                    float f = f1C[nt][t][r] + (nt ? b1 : b0);
                    f = fmaxf(f, 0.f);
                    sm[R2 + tok*R2S + nt*16 + c] = f2bs(f);
                }
    }
    __syncthreads();

    // ---- lin2 (K=32 exact) ----
    v4f o2C[4];
    #pragma unroll
    for (int t = 0; t < 4; ++t) {
        v8bf a = *(const v8bf*)&sm[R2 + (t*16 + c)*R2S + g*8];
        v4f z = {0.f, 0.f, 0.f, 0.f};
        o2C[t] = MFMA(a, Bl2, z);
    }
    __syncthreads();
    #pragma unroll
    for (int t = 0; t < 4; ++t)
        #pragma unroll
        for (int r = 0; r < 4; ++r)
            F1[(t*16 + g*4 + r)*36 + c] = o2C[t][r];
    __syncthreads();

    // ---- per-lane: +lin2_b, residual(hln), LN2, head dot; wave reduce ----
    float part = 0.f;
    {
        const float4* fr = (const float4*)&F1[lane*36];
        float hn[16];
        float mean = 0.f;
        #pragma unroll
        for (int i = 0; i < 4; ++i) {
            float4 a = fr[i];
            float av[4] = {a.x, a.y, a.z, a.w};
            #pragma unroll
            for (int e = 0; e < 4; ++e) {
                int d = i*4 + e;
                hn[d] = hln[d] + av[e] + lin2_b[d];
                mean += hn[d];
            }
        }
        mean *= (1.f/16.f);
        float var = 0.f;
        #pragma unroll
        for (int d = 0; d < 16; ++d) { float t = hn[d] - mean; var = fmaf(t, t, var); }
        var *= (1.f/16.f);
        float is = rsqrtf(var + 1e-5f);
        #pragma unroll
        for (int d = 0; d < 16; ++d) {
            float h3 = (hn[d] - mean) * is * ln2_g[d] + ln2_b[d];
            part = fmaf(h3, head_w[d], part);
        }
    }
    #pragma unroll
    for (int off = 32; off; off >>= 1) part += __shfl_down(part, off, 64);
    if (lane == 0) out[b] = part * (1.f/64.f) + head_b[0];
}

extern "C" void kernel_launch(void* const* d_in, const int* in_sizes, int n_in,
                              void* d_out, int out_size, void* d_ws, size_t ws_size,
                              hipStream_t stream) {
    const float* x         = (const float*)d_in[0];
    const float* proj_w    = (const float*)d_in[1];
    const float* proj_b    = (const float*)d_in[2];
    const float* pos       = (const float*)d_in[3];
    const float* in_proj_w = (const float*)d_in[4];
    const float* in_proj_b = (const float*)d_in[5];
    const float* out_w     = (const float*)d_in[6];
    const float* out_b     = (const float*)d_in[7];
    const float* ln1_g     = (const float*)d_in[8];
    const float* ln1_b     = (const float*)d_in[9];
    const float* lin1_w    = (const float*)d_in[10];
    const float* lin1_b    = (const float*)d_in[11];
    const float* lin2_w    = (const float*)d_in[12];
    const float* lin2_b    = (const float*)d_in[13];
    const float* ln2_g     = (const float*)d_in[14];
    const float* ln2_b     = (const float*)d_in[15];
    const float* head_w    = (const float*)d_in[16];
    const float* head_b    = (const float*)d_in[17];

    tx_mfma<<<16384, 64, 0, stream>>>(
        x, proj_w, proj_b, pos, in_proj_w, in_proj_b, out_w, out_b,
        ln1_g, ln1_b, lin1_w, lin1_b, lin2_w, lin2_b, ln2_g, ln2_b,
        head_w, head_b, (float*)d_out);
}